// Round 2
// 850.321 us; speedup vs baseline: 1.0543x; 1.0543x over previous
//
#include <hip/hip_runtime.h>

#define B_ 128
#define T_ 1024
#define D_ 128
#define H_ 128

typedef short bf16x8 __attribute__((ext_vector_type(8)));
typedef float f32x4 __attribute__((ext_vector_type(4)));

// pack 2 f32 -> 2 bf16 (RNE) in one instruction (no builtin on gfx950)
__device__ inline unsigned cvt_pk_bf16(float lo, float hi) {
    unsigned r;
    asm("v_cvt_pk_bf16_f32 %0, %1, %2" : "=v"(r) : "v"(lo), "v"(hi));
    return r;
}

// tanh(x) = 1 - 2/(1+2^(x*2*log2(e))): mul, v_exp, add, rcp, fma = 5 VALU
__device__ inline float fast_tanh(float x) {
    float e = __builtin_amdgcn_exp2f(x * 2.885390081777927f);
    float r = __builtin_amdgcn_rcpf(1.0f + e);
    return fmaf(-2.0f, r, 1.0f);
}

// lgkm-only barrier: keeps in-flight global loads/stores off the critical path
__device__ inline void lds_barrier() {
    asm volatile("s_waitcnt lgkmcnt(0)\n\ts_barrier" ::: "memory");
}

// ---------------------------------------------------------------------------
// Kernel 1: xu[rid = b*T + t][h] = x_row @ U + (bu + bw)  -> out (f32).
// Swapped-operand MFMA: D = (U^T frag) x (x^T frag) so each lane holds 4
// CONSECUTIVE h of one row -> one f32x4 store per col-tile. bw folded in so
// the scan's accumulator init is just the xu load.
// ---------------------------------------------------------------------------
__global__ __launch_bounds__(256) void xu_kernel(
    const float* __restrict__ x, const float* __restrict__ U,
    const float* __restrict__ bu, const float* __restrict__ bw,
    float* __restrict__ out)
{
    __shared__ bf16x8 uf[2048];  // [nt(8)][kk(4)][lane(64)]: U[k][16nt+(l&15)]
    const int tid  = threadIdx.x;
    const int lane = tid & 63;
    const int wave = tid >> 6;
    const int q = lane >> 4, c = lane & 15;

    for (int s = tid; s < 2048; s += 256) {
        int l = s & 63, kk = (s >> 6) & 3, nt = s >> 8;
        int lq = l >> 4, lc = l & 15;
        int kbase = 32 * kk + 8 * lq;
        int col = 16 * nt + lc;
        float v[8];
#pragma unroll
        for (int j = 0; j < 8; ++j) v[j] = U[(kbase + j) * H_ + col];
        union { bf16x8 v8; unsigned u[4]; } f;
#pragma unroll
        for (int j = 0; j < 4; ++j) f.u[j] = cvt_pk_bf16(v[2 * j], v[2 * j + 1]);
        uf[s] = f.v8;
    }

    // bias over output cols 16nt+4q+r (bu+bw folded)
    f32x4 bias4[8];
#pragma unroll
    for (int nt = 0; nt < 8; ++nt) {
        const int cb = 16 * nt + 4 * q;
        f32x4 a = *(const f32x4*)(bu + cb);
        f32x4 b = *(const f32x4*)(bw + cb);
#pragma unroll
        for (int r = 0; r < 4; ++r) bias4[nt][r] = a[r] + b[r];
    }

    __syncthreads();

    for (int it = 0; it < 4; ++it) {
        const int row0 = (blockIdx.x * 4 + it) * 64 + wave * 16;
        // B-operand frags: B[k=32kk+8q+j][n=lane&15] = x[row0+(lane&15)][k]
        bf16x8 af[4];
#pragma unroll
        for (int kk = 0; kk < 4; ++kk) {
            const float* px = x + (size_t)(row0 + c) * D_ + 32 * kk + 8 * q;
            f32x4 a0 = *(const f32x4*)px;
            f32x4 a1 = *(const f32x4*)(px + 4);
            union { bf16x8 v8; unsigned u[4]; } f;
            f.u[0] = cvt_pk_bf16(a0[0], a0[1]);
            f.u[1] = cvt_pk_bf16(a0[2], a0[3]);
            f.u[2] = cvt_pk_bf16(a1[0], a1[1]);
            f.u[3] = cvt_pk_bf16(a1[2], a1[3]);
            af[kk] = f.v8;
        }
        float* po = out + (size_t)(row0 + c) * H_ + 4 * q;
#pragma unroll
        for (int nt = 0; nt < 8; ++nt) {
            f32x4 acc = bias4[nt];
#pragma unroll
            for (int kk = 0; kk < 4; ++kk)
                acc = __builtin_amdgcn_mfma_f32_16x16x32_bf16(
                    uf[(nt * 4 + kk) * 64 + lane], af[kk], acc, 0, 0, 0);
            // D: lane&15 = row (row0+c), 4q+r = col 16nt+4q+r -> contiguous
            *(f32x4*)(po + 16 * nt) = acc;
        }
    }
}

// ---------------------------------------------------------------------------
// Kernel 2: the serial recurrence ONLY (o evicted to kernel 3).
// 8 blocks x 256 thr (4 waves, 1/SIMD). Wave w owns cols [32w, 32w+32):
// 2 col-tiles sharing the same A-frag reads -> LDS read traffic 16KB/step
// (was 64KB). Swapped MFMA => per-lane 4 consecutive cols: cvt_pk + b64 LDS
// writes, dwordx2 global st stores, f32x4 xu loads as the C-init.
// st_t (bf16) is stored into the FIRST 256B of out row (b,t) one step late:
// the end-of-step barrier guarantees every wave's lgkm-confirmed consumption
// of the st slot, and xu plane t is dead once step t has read it into regs.
// ---------------------------------------------------------------------------
__global__ __launch_bounds__(256) void scan_kernel(
    float* __restrict__ out, const float* __restrict__ h0,
    const float* __restrict__ W)
{
    // st slots: [parity][m=16][k=128 + 8 pad] bf16 (272B row stride)
    __shared__ __align__(16) short st[2][16][136];

    const int tid  = threadIdx.x;
    const int lane = tid & 63;
    const int wave = tid >> 6;           // 0..3
    const int q = lane >> 4, c = lane & 15;
    const int b0 = blockIdx.x * 16;
    const int cw = wave * 32 + 4 * q;    // per-lane col base (tile 0)

    // A-frags of W^T (regs, all 1024 steps): A[i=lane&15][k] = W[k][c0+i]
    bf16x8 wf[2][4];
#pragma unroll
    for (int tt = 0; tt < 2; ++tt) {
        const int c0 = wave * 32 + tt * 16;
#pragma unroll
        for (int kk = 0; kk < 4; ++kk) {
            const int kbase = 32 * kk + 8 * q;
            float v[8];
#pragma unroll
            for (int j = 0; j < 8; ++j) v[j] = W[(kbase + j) * H_ + c0 + c];
            union { bf16x8 v8; unsigned u[4]; } f;
#pragma unroll
            for (int j = 0; j < 4; ++j) f.u[j] = cvt_pk_bf16(v[2 * j], v[2 * j + 1]);
            wf[tt][kk] = f.v8;
        }
    }

    // stage h0 -> slot[1] (st_{-1}); 256 thr x 8 shorts, packed b128 writes
    {
        const int m = tid >> 4, k0 = (tid & 15) * 8;
        const float* ph = h0 + (size_t)(b0 + m) * H_ + k0;
        f32x4 a0 = *(const f32x4*)ph;
        f32x4 a1 = *(const f32x4*)(ph + 4);
        union { bf16x8 v8; unsigned u[4]; } f;
        f.u[0] = cvt_pk_bf16(a0[0], a0[1]);
        f.u[1] = cvt_pk_bf16(a0[2], a0[3]);
        f.u[2] = cvt_pk_bf16(a1[0], a1[1]);
        f.u[3] = cvt_pk_bf16(a1[2], a1[3]);
        *(bf16x8*)&st[1][m][k0] = f.v8;
    }

    // 8-deep xu FIFO: lane reads xu[b0+c][t][cw + 16tt] as f32x4 (C-init is
    // already col-contiguous thanks to the swapped layout)
    const float* xup = out + ((size_t)(b0 + c) * T_) * H_ + cw;
    f32x4 xub[8][2];
    {
        const float* pp = xup;
#pragma unroll
        for (int u = 0; u < 8; ++u) {
            xub[u][0] = *(const f32x4*)pp;
            xub[u][1] = *(const f32x4*)(pp + 16);
            pp += H_;
        }
    }
    const float* pf = xup + 8 * H_;

    // st_t global-store state (1-step delayed), row (b0+c, t), bytes [2cw, 2cw+8)
    uint2 pkg0, pkg1;
    char* pst = (char*)out + (((size_t)(b0 + c) * T_) * H_) * 4 + cw * 2;

    const f32x4 z4 = {0.f, 0.f, 0.f, 0.f};

    lds_barrier();

    for (int tb = 0; tb < T_ / 8; ++tb) {
#pragma unroll
        for (int u = 0; u < 8; ++u) {
            const int t = tb * 8 + u;
            const int pr = (u + 1) & 1;  // slot holding st_{t-1}
            const int pw = u & 1;        // slot to write st_t

            // store st_{t-1} bf16 into out row (b,t-1) [first 256B, xu dead]
            if (t > 0) {
                *(uint2*)pst = pkg0;
                *(uint2*)(pst + 32) = pkg1;
                pst += H_ * 4;
            }

            f32x4 xu0 = xub[u][0], xu1 = xub[u][1];
            if (t < T_ - 8) {  // refill FIFO slot with plane t+8
                xub[u][0] = *(const f32x4*)pf;
                xub[u][1] = *(const f32x4*)(pf + 16);
                pf += H_;
            }

            // B-frags: B[k=32kk+8q+j][n=lane&15] = st_{t-1}[lane&15][k]
            bf16x8 af[4];
#pragma unroll
            for (int kk = 0; kk < 4; ++kk)
                af[kk] = *(const bf16x8*)&st[pr][c][32 * kk + 8 * q];

            // 2 col-tiles x 2 independent K-chains (dep depth 2)
            f32x4 aA = __builtin_amdgcn_mfma_f32_16x16x32_bf16(wf[0][0], af[0], xu0, 0, 0, 0);
            f32x4 aB = __builtin_amdgcn_mfma_f32_16x16x32_bf16(wf[0][1], af[1], z4,  0, 0, 0);
            f32x4 bA = __builtin_amdgcn_mfma_f32_16x16x32_bf16(wf[1][0], af[0], xu1, 0, 0, 0);
            f32x4 bB = __builtin_amdgcn_mfma_f32_16x16x32_bf16(wf[1][1], af[1], z4,  0, 0, 0);
            aA = __builtin_amdgcn_mfma_f32_16x16x32_bf16(wf[0][2], af[2], aA, 0, 0, 0);
            aB = __builtin_amdgcn_mfma_f32_16x16x32_bf16(wf[0][3], af[3], aB, 0, 0, 0);
            bA = __builtin_amdgcn_mfma_f32_16x16x32_bf16(wf[1][2], af[2], bA, 0, 0, 0);
            bB = __builtin_amdgcn_mfma_f32_16x16x32_bf16(wf[1][3], af[3], bB, 0, 0, 0);

            // D: lane&15 = batch row, 4q+r = col cw+r / cw+16+r (contiguous)
            float s0 = fast_tanh(aA[0] + aB[0]);
            float s1 = fast_tanh(aA[1] + aB[1]);
            float s2 = fast_tanh(aA[2] + aB[2]);
            float s3 = fast_tanh(aA[3] + aB[3]);
            float s4 = fast_tanh(bA[0] + bB[0]);
            float s5 = fast_tanh(bA[1] + bB[1]);
            float s6 = fast_tanh(bA[2] + bB[2]);
            float s7 = fast_tanh(bA[3] + bB[3]);

            pkg0.x = cvt_pk_bf16(s0, s1);
            pkg0.y = cvt_pk_bf16(s2, s3);
            pkg1.x = cvt_pk_bf16(s4, s5);
            pkg1.y = cvt_pk_bf16(s6, s7);

            *(uint2*)&st[pw][c][cw]      = pkg0;  // ds_write_b64, packed
            *(uint2*)&st[pw][c][cw + 16] = pkg1;

            lds_barrier();
        }
    }
    // final: st_{T-1}
    *(uint2*)pst = pkg0;
    *(uint2*)(pst + 32) = pkg1;
}

// ---------------------------------------------------------------------------
// Kernel 3: o[row][h] = tanh(st_row @ V + bv), IN-PLACE over out.
// st (bf16) sits in the first 256B of each 512B row; each wave loads ALL its
// A-frags (full K of its own 16 rows) into regs before any store to those
// rows -> in-place safe; rows are disjoint across waves/blocks. Full-GPU
// parallel GEMM (512 blocks) replaces the o-waves that used to sit inside the
// serial scan.
// ---------------------------------------------------------------------------
__global__ __launch_bounds__(256) void o_kernel(
    float* __restrict__ out, const float* __restrict__ V,
    const float* __restrict__ bv)
{
    __shared__ bf16x8 vf[2048];
    const int tid  = threadIdx.x;
    const int lane = tid & 63;
    const int wave = tid >> 6;
    const int q = lane >> 4, c = lane & 15;

    for (int s = tid; s < 2048; s += 256) {
        int l = s & 63, kk = (s >> 6) & 3, nt = s >> 8;
        int lq = l >> 4, lc = l & 15;
        int kbase = 32 * kk + 8 * lq;
        int col = 16 * nt + lc;
        float v[8];
#pragma unroll
        for (int j = 0; j < 8; ++j) v[j] = V[(kbase + j) * H_ + col];
        union { bf16x8 v8; unsigned u[4]; } f;
#pragma unroll
        for (int j = 0; j < 4; ++j) f.u[j] = cvt_pk_bf16(v[2 * j], v[2 * j + 1]);
        vf[s] = f.v8;
    }

    f32x4 bias4[8];
#pragma unroll
    for (int nt = 0; nt < 8; ++nt)
        bias4[nt] = *(const f32x4*)(bv + 16 * nt + 4 * q);

    __syncthreads();

    for (int it = 0; it < 4; ++it) {
        const int row0 = (blockIdx.x * 4 + it) * 64 + wave * 16;
        // B-frags: st[row0+(lane&15)][k] read bf16 directly (no conversion)
        const char* pa = (const char*)out + (size_t)(row0 + c) * (H_ * 4);
        bf16x8 af[4];
#pragma unroll
        for (int kk = 0; kk < 4; ++kk)
            af[kk] = *(const bf16x8*)(pa + 64 * kk + 16 * q);
        float* po = out + (size_t)(row0 + c) * H_ + 4 * q;
#pragma unroll
        for (int nt = 0; nt < 8; ++nt) {
            f32x4 acc = bias4[nt];
#pragma unroll
            for (int kk = 0; kk < 4; ++kk)
                acc = __builtin_amdgcn_mfma_f32_16x16x32_bf16(
                    vf[(nt * 4 + kk) * 64 + lane], af[kk], acc, 0, 0, 0);
            f32x4 o;
#pragma unroll
            for (int r = 0; r < 4; ++r) o[r] = fast_tanh(acc[r]);
            *(f32x4*)(po + 16 * nt) = o;
        }
    }
}

extern "C" void kernel_launch(void* const* d_in, const int* in_sizes, int n_in,
                              void* d_out, int out_size, void* d_ws, size_t ws_size,
                              hipStream_t stream) {
    const float* x  = (const float*)d_in[0];
    const float* h0 = (const float*)d_in[1];
    const float* U  = (const float*)d_in[2];
    const float* W  = (const float*)d_in[3];
    const float* V  = (const float*)d_in[4];
    const float* bu = (const float*)d_in[5];
    const float* bw = (const float*)d_in[6];
    const float* bv = (const float*)d_in[7];
    float* out = (float*)d_out;

    // xu = x@U + (bu+bw) into out[B*T][H] (f32)
    xu_kernel<<<512, 256, 0, stream>>>(x, U, bu, bw, out);
    // serial recurrence; st_t stored bf16 into first half of each out row
    scan_kernel<<<8, 256, 0, stream>>>(out, h0, W);
    // o = tanh(st@V + bv), in-place over out
    o_kernel<<<512, 256, 0, stream>>>(out, V, bv);
}

// Round 3
// 802.497 us; speedup vs baseline: 1.1172x; 1.0596x over previous
//
#include <hip/hip_runtime.h>

#define B_ 128
#define T_ 1024
#define D_ 128
#define H_ 128

typedef short bf16x8 __attribute__((ext_vector_type(8)));
typedef float f32x4 __attribute__((ext_vector_type(4)));

// pack 2 f32 -> 2 bf16 (RNE) in one instruction (no builtin on gfx950)
__device__ inline unsigned cvt_pk_bf16(float lo, float hi) {
    unsigned r;
    asm("v_cvt_pk_bf16_f32 %0, %1, %2" : "=v"(r) : "v"(lo), "v"(hi));
    return r;
}

// tanh(x) = 1 - 2/(1+2^(x*2*log2(e))): mul, v_exp, add, rcp, fma = 5 VALU
__device__ inline float fast_tanh(float x) {
    float e = __builtin_amdgcn_exp2f(x * 2.885390081777927f);
    float r = __builtin_amdgcn_rcpf(1.0f + e);
    return fmaf(-2.0f, r, 1.0f);
}

// lgkm-only barrier: keeps in-flight global loads/stores off the critical path
__device__ inline void lds_barrier() {
    asm volatile("s_waitcnt lgkmcnt(0)\n\ts_barrier" ::: "memory");
}

// ---------------------------------------------------------------------------
// Kernel 1: xu[rid = b*T + t][h] = x_row @ U + (bu + bw)  -> out (f32).
// Swapped-operand MFMA: D = (U^T frag) x (x^T frag) so each lane holds 4
// CONSECUTIVE h of one row -> one f32x4 store per col-tile. bw folded in.
// ---------------------------------------------------------------------------
__global__ __launch_bounds__(256) void xu_kernel(
    const float* __restrict__ x, const float* __restrict__ U,
    const float* __restrict__ bu, const float* __restrict__ bw,
    float* __restrict__ out)
{
    __shared__ bf16x8 uf[2048];  // [nt(8)][kk(4)][lane(64)]: U[k][16nt+(l&15)]
    const int tid  = threadIdx.x;
    const int lane = tid & 63;
    const int wave = tid >> 6;
    const int q = lane >> 4, c = lane & 15;

    for (int s = tid; s < 2048; s += 256) {
        int l = s & 63, kk = (s >> 6) & 3, nt = s >> 8;
        int lq = l >> 4, lc = l & 15;
        int kbase = 32 * kk + 8 * lq;
        int col = 16 * nt + lc;
        float v[8];
#pragma unroll
        for (int j = 0; j < 8; ++j) v[j] = U[(kbase + j) * H_ + col];
        union { bf16x8 v8; unsigned u[4]; } f;
#pragma unroll
        for (int j = 0; j < 4; ++j) f.u[j] = cvt_pk_bf16(v[2 * j], v[2 * j + 1]);
        uf[s] = f.v8;
    }

    // bias over output cols 16nt+4q+r (bu+bw folded)
    f32x4 bias4[8];
#pragma unroll
    for (int nt = 0; nt < 8; ++nt) {
        const int cb = 16 * nt + 4 * q;
        f32x4 a = *(const f32x4*)(bu + cb);
        f32x4 b = *(const f32x4*)(bw + cb);
#pragma unroll
        for (int r = 0; r < 4; ++r) bias4[nt][r] = a[r] + b[r];
    }

    __syncthreads();

    for (int it = 0; it < 4; ++it) {
        const int row0 = (blockIdx.x * 4 + it) * 64 + wave * 16;
        // B-operand frags: B[k=32kk+8q+j][n=lane&15] = x[row0+(lane&15)][k]
        bf16x8 af[4];
#pragma unroll
        for (int kk = 0; kk < 4; ++kk) {
            const float* px = x + (size_t)(row0 + c) * D_ + 32 * kk + 8 * q;
            f32x4 a0 = *(const f32x4*)px;
            f32x4 a1 = *(const f32x4*)(px + 4);
            union { bf16x8 v8; unsigned u[4]; } f;
            f.u[0] = cvt_pk_bf16(a0[0], a0[1]);
            f.u[1] = cvt_pk_bf16(a0[2], a0[3]);
            f.u[2] = cvt_pk_bf16(a1[0], a1[1]);
            f.u[3] = cvt_pk_bf16(a1[2], a1[3]);
            af[kk] = f.v8;
        }
        float* po = out + (size_t)(row0 + c) * H_ + 4 * q;
#pragma unroll
        for (int nt = 0; nt < 8; ++nt) {
            f32x4 acc = bias4[nt];
#pragma unroll
            for (int kk = 0; kk < 4; ++kk)
                acc = __builtin_amdgcn_mfma_f32_16x16x32_bf16(
                    uf[(nt * 4 + kk) * 64 + lane], af[kk], acc, 0, 0, 0);
            // D: lane&15 = row (row0+c), 4q+r = col 16nt+4q+r -> contiguous
            *(f32x4*)(po + 16 * nt) = acc;
        }
    }
}

// ---------------------------------------------------------------------------
// Kernel 2: serial recurrence. 8 blocks x 256 thr (4 waves, 1/SIMD).
// ALIAS-SPLIT: xu_in (loads, plane t+8) and st_out (stores, plane t-1) are
// the SAME runtime pointer but distinct __restrict__ params, so the compiler
// does not serialize the FIFO-refill loads behind the in-flight st stores
// with a vmcnt drain each step. Temporal safety: the two access streams are
// 9 steps (9 asm memory-clobber barriers) apart and never touch the same
// plane concurrently.
// ---------------------------------------------------------------------------
__global__ __launch_bounds__(256) void scan_kernel(
    const float* __restrict__ xu_in, float* __restrict__ st_out,
    const float* __restrict__ h0, const float* __restrict__ W)
{
    // st slots: [parity][m=16][k=128 + 8 pad] bf16 (272B row stride)
    __shared__ __align__(16) short st[2][16][136];

    const int tid  = threadIdx.x;
    const int lane = tid & 63;
    const int wave = tid >> 6;           // 0..3
    const int q = lane >> 4, c = lane & 15;
    const int b0 = blockIdx.x * 16;
    const int cw = wave * 32 + 4 * q;    // per-lane col base (tile 0)

    // A-frags of W^T (regs, all 1024 steps): A[i=lane&15][k] = W[k][c0+i]
    bf16x8 wf[2][4];
#pragma unroll
    for (int tt = 0; tt < 2; ++tt) {
        const int c0 = wave * 32 + tt * 16;
#pragma unroll
        for (int kk = 0; kk < 4; ++kk) {
            const int kbase = 32 * kk + 8 * q;
            float v[8];
#pragma unroll
            for (int j = 0; j < 8; ++j) v[j] = W[(kbase + j) * H_ + c0 + c];
            union { bf16x8 v8; unsigned u[4]; } f;
#pragma unroll
            for (int j = 0; j < 4; ++j) f.u[j] = cvt_pk_bf16(v[2 * j], v[2 * j + 1]);
            wf[tt][kk] = f.v8;
        }
    }

    // stage h0 -> slot[1] (st_{-1}); 256 thr x 8 shorts, packed b128 writes
    {
        const int m = tid >> 4, k0 = (tid & 15) * 8;
        const float* ph = h0 + (size_t)(b0 + m) * H_ + k0;
        f32x4 a0 = *(const f32x4*)ph;
        f32x4 a1 = *(const f32x4*)(ph + 4);
        union { bf16x8 v8; unsigned u[4]; } f;
        f.u[0] = cvt_pk_bf16(a0[0], a0[1]);
        f.u[1] = cvt_pk_bf16(a0[2], a0[3]);
        f.u[2] = cvt_pk_bf16(a1[0], a1[1]);
        f.u[3] = cvt_pk_bf16(a1[2], a1[3]);
        *(bf16x8*)&st[1][m][k0] = f.v8;
    }

    // 8-deep xu FIFO: lane reads xu[b0+c][t][cw + 16tt] as f32x4
    const float* xup = xu_in + ((size_t)(b0 + c) * T_) * H_ + cw;
    f32x4 xub[8][2];
    {
        const float* pp = xup;
#pragma unroll
        for (int u = 0; u < 8; ++u) {
            xub[u][0] = *(const f32x4*)pp;
            xub[u][1] = *(const f32x4*)(pp + 16);
            pp += H_;
        }
    }
    const float* pf = xup + 8 * H_;

    // st_t global-store state (1-step delayed), row (b0+c, t), bytes [2cw, 2cw+8)
    uint2 pkg0, pkg1;
    char* pst = (char*)st_out + (((size_t)(b0 + c) * T_) * H_) * 4 + cw * 2;

    const f32x4 z4 = {0.f, 0.f, 0.f, 0.f};

    lds_barrier();

    for (int tb = 0; tb < T_ / 8; ++tb) {
#pragma unroll
        for (int u = 0; u < 8; ++u) {
            const int t = tb * 8 + u;
            const int pr = (u + 1) & 1;  // slot holding st_{t-1}
            const int pw = u & 1;        // slot to write st_t

            // store st_{t-1} bf16 into row (b, t-1) [first 256B of the row]
            if (t > 0) {
                *(uint2*)pst = pkg0;
                *(uint2*)(pst + 32) = pkg1;
                pst += H_ * 4;
            }

            f32x4 xu0 = xub[u][0], xu1 = xub[u][1];
            if (t < T_ - 8) {  // refill FIFO slot with plane t+8
                xub[u][0] = *(const f32x4*)pf;
                xub[u][1] = *(const f32x4*)(pf + 16);
                pf += H_;
            }

            // B-frags: B[k=32kk+8q+j][n=lane&15] = st_{t-1}[lane&15][k]
            bf16x8 af[4];
#pragma unroll
            for (int kk = 0; kk < 4; ++kk)
                af[kk] = *(const bf16x8*)&st[pr][c][32 * kk + 8 * q];

            // 2 col-tiles x 2 independent K-chains (dep depth 2)
            f32x4 aA = __builtin_amdgcn_mfma_f32_16x16x32_bf16(wf[0][0], af[0], xu0, 0, 0, 0);
            f32x4 aB = __builtin_amdgcn_mfma_f32_16x16x32_bf16(wf[0][1], af[1], z4,  0, 0, 0);
            f32x4 bA = __builtin_amdgcn_mfma_f32_16x16x32_bf16(wf[1][0], af[0], xu1, 0, 0, 0);
            f32x4 bB = __builtin_amdgcn_mfma_f32_16x16x32_bf16(wf[1][1], af[1], z4,  0, 0, 0);
            aA = __builtin_amdgcn_mfma_f32_16x16x32_bf16(wf[0][2], af[2], aA, 0, 0, 0);
            aB = __builtin_amdgcn_mfma_f32_16x16x32_bf16(wf[0][3], af[3], aB, 0, 0, 0);
            bA = __builtin_amdgcn_mfma_f32_16x16x32_bf16(wf[1][2], af[2], bA, 0, 0, 0);
            bB = __builtin_amdgcn_mfma_f32_16x16x32_bf16(wf[1][3], af[3], bB, 0, 0, 0);

            // D: lane&15 = batch row, 4q+r = col cw+r / cw+16+r (contiguous)
            float s0 = fast_tanh(aA[0] + aB[0]);
            float s1 = fast_tanh(aA[1] + aB[1]);
            float s2 = fast_tanh(aA[2] + aB[2]);
            float s3 = fast_tanh(aA[3] + aB[3]);
            float s4 = fast_tanh(bA[0] + bB[0]);
            float s5 = fast_tanh(bA[1] + bB[1]);
            float s6 = fast_tanh(bA[2] + bB[2]);
            float s7 = fast_tanh(bA[3] + bB[3]);

            pkg0.x = cvt_pk_bf16(s0, s1);
            pkg0.y = cvt_pk_bf16(s2, s3);
            pkg1.x = cvt_pk_bf16(s4, s5);
            pkg1.y = cvt_pk_bf16(s6, s7);

            *(uint2*)&st[pw][c][cw]      = pkg0;  // ds_write_b64, packed
            *(uint2*)&st[pw][c][cw + 16] = pkg1;

            lds_barrier();
        }
    }
    // final: st_{T-1}
    *(uint2*)pst = pkg0;
    *(uint2*)(pst + 32) = pkg1;
}

// ---------------------------------------------------------------------------
// Kernel 3: o[row][h] = tanh(st_row @ V + bv), in-place over out.
// st_in/o_out are the same runtime pointer (alias-split); the MFMA data
// dependency forces every lane's st loads to complete before its row stores.
// Rows are disjoint across waves/blocks.
// ---------------------------------------------------------------------------
__global__ __launch_bounds__(256) void o_kernel(
    const float* __restrict__ st_in, float* __restrict__ o_out,
    const float* __restrict__ V, const float* __restrict__ bv)
{
    __shared__ bf16x8 vf[2048];
    const int tid  = threadIdx.x;
    const int lane = tid & 63;
    const int wave = tid >> 6;
    const int q = lane >> 4, c = lane & 15;

    for (int s = tid; s < 2048; s += 256) {
        int l = s & 63, kk = (s >> 6) & 3, nt = s >> 8;
        int lq = l >> 4, lc = l & 15;
        int kbase = 32 * kk + 8 * lq;
        int col = 16 * nt + lc;
        float v[8];
#pragma unroll
        for (int j = 0; j < 8; ++j) v[j] = V[(kbase + j) * H_ + col];
        union { bf16x8 v8; unsigned u[4]; } f;
#pragma unroll
        for (int j = 0; j < 4; ++j) f.u[j] = cvt_pk_bf16(v[2 * j], v[2 * j + 1]);
        vf[s] = f.v8;
    }

    f32x4 bias4[8];
#pragma unroll
    for (int nt = 0; nt < 8; ++nt)
        bias4[nt] = *(const f32x4*)(bv + 16 * nt + 4 * q);

    __syncthreads();

    for (int it = 0; it < 4; ++it) {
        const int row0 = (blockIdx.x * 4 + it) * 64 + wave * 16;
        // B-frags: st[row0+(lane&15)][k] read bf16 directly from row head
        const char* pa = (const char*)st_in + (size_t)(row0 + c) * (H_ * 4);
        bf16x8 af[4];
#pragma unroll
        for (int kk = 0; kk < 4; ++kk)
            af[kk] = *(const bf16x8*)(pa + 64 * kk + 16 * q);
        float* po = o_out + (size_t)(row0 + c) * H_ + 4 * q;
#pragma unroll
        for (int nt = 0; nt < 8; ++nt) {
            f32x4 acc = bias4[nt];
#pragma unroll
            for (int kk = 0; kk < 4; ++kk)
                acc = __builtin_amdgcn_mfma_f32_16x16x32_bf16(
                    vf[(nt * 4 + kk) * 64 + lane], af[kk], acc, 0, 0, 0);
            f32x4 o;
#pragma unroll
            for (int r = 0; r < 4; ++r) o[r] = fast_tanh(acc[r]);
            *(f32x4*)(po + 16 * nt) = o;
        }
    }
}

extern "C" void kernel_launch(void* const* d_in, const int* in_sizes, int n_in,
                              void* d_out, int out_size, void* d_ws, size_t ws_size,
                              hipStream_t stream) {
    const float* x  = (const float*)d_in[0];
    const float* h0 = (const float*)d_in[1];
    const float* U  = (const float*)d_in[2];
    const float* W  = (const float*)d_in[3];
    const float* V  = (const float*)d_in[4];
    const float* bu = (const float*)d_in[5];
    const float* bw = (const float*)d_in[6];
    const float* bv = (const float*)d_in[7];
    float* out = (float*)d_out;

    // xu = x@U + (bu+bw) into out[B*T][H] (f32)
    xu_kernel<<<512, 256, 0, stream>>>(x, U, bu, bw, out);
    // serial recurrence; st_t stored bf16 into first half of each out row
    // (alias-split: same pointer, distinct restrict params)
    scan_kernel<<<8, 256, 0, stream>>>(out, out, h0, W);
    // o = tanh(st@V + bv), in-place over out (alias-split)
    o_kernel<<<512, 256, 0, stream>>>(out, out, V, bv);
}